// Round 10
// baseline (566.388 us; speedup 1.0000x reference)
//
#include <hip/hip_runtime.h>

constexpr int D   = 128;
constexpr int NA  = 100000;
constexpr int NB  = 100000;
constexpr int NE  = 400000;
constexpr int CAP = 24;        // P(Poisson(4) >= 24) ~ 1.6e-14 -> never truncates

typedef __attribute__((ext_vector_type(8))) short           bf16x8;
typedef __attribute__((ext_vector_type(4))) float           f32x4;
typedef __attribute__((ext_vector_type(4))) unsigned short  us4;

static __device__ __forceinline__ unsigned short f2bf(float f) {
    unsigned u = __float_as_uint(f);
    unsigned r = (u + 0x7FFFu + ((u >> 16) & 1u)) >> 16;   // RN-even
    return (unsigned short)r;
}

// ---------------------------------------------------------------------------
// Weight prep: WT[m][c][k] = bf16(W_m[k][c]); m=4 is Wself_ab1+Wself_ab2
// ---------------------------------------------------------------------------
__global__ __launch_bounds__(256) void prep_weights_kernel(
    unsigned short* __restrict__ WT,
    const float* __restrict__ Wmba,  const float* __restrict__ Wsba,
    const float* __restrict__ Wmab1, const float* __restrict__ Wmab2,
    const float* __restrict__ Wsab1, const float* __restrict__ Wsab2)
{
    int idx = blockIdx.x * 256 + threadIdx.x;      // 0 .. 5*16384-1
    int m   = idx >> 14;
    int rem = idx & 16383;
    int c   = rem >> 7;
    int k   = rem & 127;
    float v;
    if      (m == 0) v = Wmba [k * D + c];
    else if (m == 1) v = Wsba [k * D + c];
    else if (m == 2) v = Wmab1[k * D + c];
    else if (m == 3) v = Wmab2[k * D + c];
    else             v = Wsab1[k * D + c] + Wsab2[k * D + c];
    WT[idx] = f2bf(v);
}

// ---------------------------------------------------------------------------
// ELL fill: slots[dst][cursor[dst]++] = src
// ---------------------------------------------------------------------------
__global__ __launch_bounds__(256) void fill_kernel(
    int* __restrict__ cursor, int* __restrict__ slots,
    const int* __restrict__ src, const int* __restrict__ dst, int E)
{
    int e = blockIdx.x * 256 + threadIdx.x;
    if (e >= E) return;
    int d = dst[e];
    int pos = atomicAdd(&cursor[d], 1);
    if (pos < CAP) slots[(size_t)d * CAP + pos] = src[e];
}

// ---------------------------------------------------------------------------
// Fused gather + GEMM:
//   out[row0..row0+64) = sum_p gathersum_p(XM) @ WTmsg_p + bf16(XS) @ WTself
// Gather phase: 32 lanes/row, fp32 accumulate, bf16 XOR-swizzled LDS tile.
// MFMA phase: 4 waves x 16 rows, A from LDS, W from L2, self direct.
// ---------------------------------------------------------------------------
template<int NBF>
__global__ __launch_bounds__(256) void fused_gnn_kernel(
    float* __restrict__ out,
    const float* __restrict__ XM,
    const int* __restrict__ cur0, const int* __restrict__ sl0,
    const int* __restrict__ cur1, const int* __restrict__ sl1,
    const float* __restrict__ XS,
    const unsigned short* __restrict__ WT0,
    const unsigned short* __restrict__ WT1,
    const unsigned short* __restrict__ WTS,
    int N)
{
    __shared__ unsigned short tile[NBF][64][128];   // 16 KB per panel, swizzled

    const int tid  = threadIdx.x;
    const int row0 = blockIdx.x * 64;

    // ---- gather phase: 8 rows per iteration (32 lanes per row) ----------
    {
        const int lj   = tid & 31;        // float4 index within row (0..31)
        const int rsub = tid >> 5;        // 0..7
        #pragma unroll
        for (int p = 0; p < NBF; ++p) {
            const int* __restrict__ cur = (p == 0) ? cur0 : cur1;
            const int* __restrict__ sl  = (p == 0) ? sl0  : sl1;
            #pragma unroll
            for (int it = 0; it < 8; ++it) {
                int rl = it * 8 + rsub;               // 0..63
                int r  = row0 + rl;
                float4 a0 = make_float4(0.f, 0.f, 0.f, 0.f);
                float4 a1 = make_float4(0.f, 0.f, 0.f, 0.f);
                if (r < N) {
                    int deg = min(cur[r], CAP);
                    const int* s = sl + (size_t)r * CAP;
                    int i = 0;
                    for (; i + 1 < deg; i += 2) {
                        int s0 = s[i], s1 = s[i + 1];
                        float4 v0 = *reinterpret_cast<const float4*>(XM + (size_t)s0 * D + lj * 4);
                        float4 v1 = *reinterpret_cast<const float4*>(XM + (size_t)s1 * D + lj * 4);
                        a0.x += v0.x; a0.y += v0.y; a0.z += v0.z; a0.w += v0.w;
                        a1.x += v1.x; a1.y += v1.y; a1.z += v1.z; a1.w += v1.w;
                    }
                    if (i < deg) {
                        float4 v0 = *reinterpret_cast<const float4*>(XM + (size_t)s[i] * D + lj * 4);
                        a0.x += v0.x; a0.y += v0.y; a0.z += v0.z; a0.w += v0.w;
                    }
                    a0.x += a1.x; a0.y += a1.y; a0.z += a1.z; a0.w += a1.w;
                }
                us4 o;
                o.x = f2bf(a0.x); o.y = f2bf(a0.y); o.z = f2bf(a0.z); o.w = f2bf(a0.w);
                int cb = (lj * 8) ^ ((rl & 7) << 4);   // swizzled byte offset in row
                *reinterpret_cast<us4*>(reinterpret_cast<char*>(&tile[p][rl][0]) + cb) = o;
            }
        }
    }
    __syncthreads();

    // ---- MFMA phase -----------------------------------------------------
    const int lane = tid & 63;
    const int wid  = tid >> 6;
    const int g    = lane >> 4;          // k-subgroup 0..3
    const int m    = lane & 15;          // A row / B,D col
    const int rl0  = wid * 16;           // wave's row base within tile

    f32x4 acc[8];
    #pragma unroll
    for (int ct = 0; ct < 8; ++ct) acc[ct] = (f32x4){0.f, 0.f, 0.f, 0.f};

    #pragma unroll
    for (int p = 0; p < NBF; ++p) {
        bf16x8 af[4];
        const char* rowp = reinterpret_cast<const char*>(&tile[p][rl0 + m][0]);
        #pragma unroll
        for (int ks = 0; ks < 4; ++ks) {
            int cb = (g * 16 + ks * 64) ^ ((m & 7) << 4);
            af[ks] = *reinterpret_cast<const bf16x8*>(rowp + cb);
        }
        const unsigned short* __restrict__ W = (p == 0) ? WT0 : WT1;
        #pragma unroll
        for (int ct = 0; ct < 8; ++ct) {
            const unsigned short* wp = W + (size_t)(ct * 16 + m) * D + g * 8;
            #pragma unroll
            for (int ks = 0; ks < 4; ++ks) {
                bf16x8 bfv = *reinterpret_cast<const bf16x8*>(wp + ks * 32);
                acc[ct] = __builtin_amdgcn_mfma_f32_16x16x32_bf16(af[ks], bfv, acc[ct], 0, 0, 0);
            }
        }
    }

    // self panel: fp32 -> bf16 inline, direct from global
    {
        int r = row0 + rl0 + m;
        r = (r < N) ? r : (N - 1);
        const float* ap = XS + (size_t)r * D + g * 8;
        bf16x8 af[4];
        #pragma unroll
        for (int ks = 0; ks < 4; ++ks) {
            float4 lo = *reinterpret_cast<const float4*>(ap + ks * 32);
            float4 hi = *reinterpret_cast<const float4*>(ap + ks * 32 + 4);
            bf16x8 f;
            f[0] = (short)f2bf(lo.x); f[1] = (short)f2bf(lo.y);
            f[2] = (short)f2bf(lo.z); f[3] = (short)f2bf(lo.w);
            f[4] = (short)f2bf(hi.x); f[5] = (short)f2bf(hi.y);
            f[6] = (short)f2bf(hi.z); f[7] = (short)f2bf(hi.w);
            af[ks] = f;
        }
        #pragma unroll
        for (int ct = 0; ct < 8; ++ct) {
            const unsigned short* wp = WTS + (size_t)(ct * 16 + m) * D + g * 8;
            #pragma unroll
            for (int ks = 0; ks < 4; ++ks) {
                bf16x8 bfv = *reinterpret_cast<const bf16x8*>(wp + ks * 32);
                acc[ct] = __builtin_amdgcn_mfma_f32_16x16x32_bf16(af[ks], bfv, acc[ct], 0, 0, 0);
            }
        }
    }

    // epilogue: C/D layout col=lane&15, row=(lane>>4)*4+reg
    const int r0 = row0 + rl0 + g * 4;
    #pragma unroll
    for (int ct = 0; ct < 8; ++ct) {
        int col = ct * 16 + m;
        #pragma unroll
        for (int j = 0; j < 4; ++j) {
            int r = r0 + j;
            if (r < N) out[(size_t)r * D + col] = acc[ct][j];
        }
    }
}

// ---------------------------------------------------------------------------
extern "C" void kernel_launch(void* const* d_in, const int* in_sizes, int n_in,
                              void* d_out, int out_size, void* d_ws, size_t ws_size,
                              hipStream_t stream)
{
    const float* x_A        = (const float*)d_in[0];
    const float* x_B        = (const float*)d_in[1];
    const float* W_msg_ab1  = (const float*)d_in[2];
    const float* W_self_ab1 = (const float*)d_in[3];
    const float* W_msg_ab2  = (const float*)d_in[4];
    const float* W_self_ab2 = (const float*)d_in[5];
    const float* W_msg_ba   = (const float*)d_in[6];
    const float* W_self_ba  = (const float*)d_in[7];
    const int* src_ab1 = (const int*)d_in[8];
    const int* dst_ab1 = (const int*)d_in[9];
    const int* src_ab2 = (const int*)d_in[10];
    const int* dst_ab2 = (const int*)d_in[11];
    const int* src_ba  = (const int*)d_in[12];
    const int* dst_ba  = (const int*)d_in[13];

    float* out_A = (float*)d_out;
    float* out_B = out_A + (size_t)NA * D;

    // workspace layout (~30.2 MB)
    char* ws = (char*)d_ws;
    int* cur = (int*)ws;                       // 3 cursors, contiguous: 1.2 MB
    int* cur0 = cur;            // ba
    int* cur1 = cur + NA;       // ab1
    int* cur2 = cur + 2 * NA;   // ab2
    int* sl0 = cur + 3 * NA;                   // 9.6 MB each
    int* sl1 = sl0 + (size_t)NA * CAP;
    int* sl2 = sl1 + (size_t)NA * CAP;
    unsigned short* WT = (unsigned short*)(sl2 + (size_t)NA * CAP);    // 160 KB
    unsigned short* WT_mba  = WT;
    unsigned short* WT_sba  = WT + 1 * D * D;
    unsigned short* WT_mab1 = WT + 2 * D * D;
    unsigned short* WT_mab2 = WT + 3 * D * D;
    unsigned short* WT_sab  = WT + 4 * D * D;

    const dim3 blk(256);
    const int fill_blocks = (NE + 255) / 256;          // 1563
    const int gnn_blocks  = (NA + 63) / 64;            // 1563

    prep_weights_kernel<<<5 * D * D / 256, blk, 0, stream>>>(
        WT, W_msg_ba, W_self_ba, W_msg_ab1, W_msg_ab2, W_self_ab1, W_self_ab2);

    hipMemsetAsync(cur, 0, 3 * (size_t)NA * sizeof(int), stream);
    fill_kernel<<<fill_blocks, blk, 0, stream>>>(cur0, sl0, src_ba,  dst_ba,  NE);
    fill_kernel<<<fill_blocks, blk, 0, stream>>>(cur1, sl1, src_ab1, dst_ab1, NE);
    fill_kernel<<<fill_blocks, blk, 0, stream>>>(cur2, sl2, src_ab2, dst_ab2, NE);

    // out_A = segsum(x_B[src_ba]) @ Wm_ba + x_A @ Ws_ba
    fused_gnn_kernel<1><<<gnn_blocks, blk, 0, stream>>>(
        out_A, x_B, cur0, sl0, nullptr, nullptr, x_A, WT_mba, nullptr, WT_sba, NA);

    // out_B = segsum(x_A[src_ab1]) @ Wm_ab1 + segsum(x_A[src_ab2]) @ Wm_ab2
    //       + x_B @ (Ws_ab1 + Ws_ab2)
    fused_gnn_kernel<2><<<gnn_blocks, blk, 0, stream>>>(
        out_B, x_A, cur1, sl1, cur2, sl2, x_B, WT_mab1, WT_mab2, WT_sab, NB);
}

// Round 14
// 504.612 us; speedup vs baseline: 1.1224x; 1.1224x over previous
//
#include <hip/hip_runtime.h>

constexpr int D   = 128;
constexpr int NA  = 100000;
constexpr int NB  = 100000;
constexpr int NE  = 400000;
constexpr int CAP = 24;        // P(Poisson(4) >= 24) ~ 1.6e-14 -> never truncates

typedef __attribute__((ext_vector_type(8))) short           bf16x8;
typedef __attribute__((ext_vector_type(4))) float           f32x4;
typedef __attribute__((ext_vector_type(4))) unsigned short  us4;

static __device__ __forceinline__ unsigned short f2bf(float f) {
    unsigned u = __float_as_uint(f);
    unsigned r = (u + 0x7FFFu + ((u >> 16) & 1u)) >> 16;   // RN-even
    return (unsigned short)r;
}
static __device__ __forceinline__ float bf2f(unsigned short u) {
    return __uint_as_float((unsigned)u << 16);
}

// ---------------------------------------------------------------------------
// Weight prep: WT[m][c][k] = bf16(W_m[k][c]); m=4 is Wself_ab1+Wself_ab2
// ---------------------------------------------------------------------------
__global__ __launch_bounds__(256) void prep_weights_kernel(
    unsigned short* __restrict__ WT,
    const float* __restrict__ Wmba,  const float* __restrict__ Wsba,
    const float* __restrict__ Wmab1, const float* __restrict__ Wmab2,
    const float* __restrict__ Wsab1, const float* __restrict__ Wsab2)
{
    int idx = blockIdx.x * 256 + threadIdx.x;      // 0 .. 5*16384-1
    int m   = idx >> 14;
    int rem = idx & 16383;
    int c   = rem >> 7;
    int k   = rem & 127;
    float v;
    if      (m == 0) v = Wmba [k * D + c];
    else if (m == 1) v = Wsba [k * D + c];
    else if (m == 2) v = Wmab1[k * D + c];
    else if (m == 3) v = Wmab2[k * D + c];
    else             v = Wsab1[k * D + c] + Wsab2[k * D + c];
    WT[idx] = f2bf(v);
}

// ---------------------------------------------------------------------------
// Convert x_A | x_B (fp32) -> xb (bf16), 8 elems/thread
// ---------------------------------------------------------------------------
__global__ __launch_bounds__(256) void convert_x_kernel(
    unsigned short* __restrict__ xb,
    const float* __restrict__ xA, const float* __restrict__ xB)
{
    const size_t half = (size_t)NA * D;
    size_t i = ((size_t)blockIdx.x * 256 + threadIdx.x) * 8;
    const float* src = (i < half) ? (xA + i) : (xB + (i - half));
    float4 lo = *reinterpret_cast<const float4*>(src);
    float4 hi = *reinterpret_cast<const float4*>(src + 4);
    bf16x8 o;
    o[0] = (short)f2bf(lo.x); o[1] = (short)f2bf(lo.y);
    o[2] = (short)f2bf(lo.z); o[3] = (short)f2bf(lo.w);
    o[4] = (short)f2bf(hi.x); o[5] = (short)f2bf(hi.y);
    o[6] = (short)f2bf(hi.z); o[7] = (short)f2bf(hi.w);
    *reinterpret_cast<bf16x8*>(xb + i) = o;
}

// ---------------------------------------------------------------------------
// Fused ELL fill for all 3 edge types (one dispatch)
// ---------------------------------------------------------------------------
__global__ __launch_bounds__(256) void fill_all_kernel(
    int* __restrict__ cur, int* __restrict__ slots,
    const int* __restrict__ s0, const int* __restrict__ d0,
    const int* __restrict__ s1, const int* __restrict__ d1,
    const int* __restrict__ s2, const int* __restrict__ d2)
{
    int idx = blockIdx.x * 256 + threadIdx.x;
    if (idx >= 3 * NE) return;
    int t = idx / NE;
    int e = idx - t * NE;
    const int* sp = (t == 0) ? s0 : (t == 1) ? s1 : s2;
    const int* dp = (t == 0) ? d0 : (t == 1) ? d1 : d2;
    int d = dp[e];
    int pos = atomicAdd(&cur[t * NA + d], 1);
    if (pos < CAP) slots[((size_t)t * NA + d) * CAP + pos] = sp[e];
}

// ---------------------------------------------------------------------------
// Gather-sum (bf16 in, bf16 out): G[r] = bf16( sum_i Xb[slots[r][i]] )
// 16 lanes per row, bf16x8 per lane, fp32 accumulate
// ---------------------------------------------------------------------------
__global__ __launch_bounds__(256) void gather_sum_kernel(
    unsigned short* __restrict__ G, const unsigned short* __restrict__ Xb,
    const int* __restrict__ cur, const int* __restrict__ slots, int N)
{
    int t = blockIdx.x * 256 + threadIdx.x;
    int r = t >> 4;
    if (r >= N) return;
    int j = (t & 15) * 8;                        // elem base 0..120
    int deg = min(cur[r], CAP);
    const int* sl = slots + (size_t)r * CAP;
    float a0[8] = {0,0,0,0,0,0,0,0};
    float a1[8] = {0,0,0,0,0,0,0,0};
    int i = 0;
    for (; i + 1 < deg; i += 2) {
        int s0 = sl[i], s1 = sl[i + 1];
        bf16x8 v0 = *reinterpret_cast<const bf16x8*>(Xb + (size_t)s0 * D + j);
        bf16x8 v1 = *reinterpret_cast<const bf16x8*>(Xb + (size_t)s1 * D + j);
        #pragma unroll
        for (int k = 0; k < 8; ++k) {
            a0[k] += bf2f((unsigned short)v0[k]);
            a1[k] += bf2f((unsigned short)v1[k]);
        }
    }
    if (i < deg) {
        bf16x8 v0 = *reinterpret_cast<const bf16x8*>(Xb + (size_t)sl[i] * D + j);
        #pragma unroll
        for (int k = 0; k < 8; ++k) a0[k] += bf2f((unsigned short)v0[k]);
    }
    bf16x8 o;
    #pragma unroll
    for (int k = 0; k < 8; ++k) o[k] = (short)f2bf(a0[k] + a1[k]);
    *reinterpret_cast<bf16x8*>(G + (size_t)r * D + j) = o;
}

// ---------------------------------------------------------------------------
// MFMA GEMM: out[N,128] = sum_{p<NP} A_p @ W_p     (all A bf16 row-major,
// all W bf16 [col][k]).  64 rows/block, 4 waves x 16 rows, no LDS.
// ---------------------------------------------------------------------------
template<int NP>
__global__ __launch_bounds__(256) void mfma_gemm_kernel(
    float* __restrict__ out,
    const unsigned short* __restrict__ A0, const unsigned short* __restrict__ A1,
    const unsigned short* __restrict__ A2,
    const unsigned short* __restrict__ W0, const unsigned short* __restrict__ W1,
    const unsigned short* __restrict__ W2,
    int N)
{
    const int tid  = threadIdx.x;
    const int lane = tid & 63;
    const int wid  = tid >> 6;
    const int g    = lane >> 4;      // 0..3: k-subgroup
    const int m    = lane & 15;      // row (A) / col (B,D)
    const int rbase = blockIdx.x * 64 + wid * 16;

    int r = rbase + m;
    r = (r < N) ? r : (N - 1);

    f32x4 acc[8];
    #pragma unroll
    for (int ct = 0; ct < 8; ++ct) acc[ct] = (f32x4){0.f, 0.f, 0.f, 0.f};

    #pragma unroll
    for (int p = 0; p < NP; ++p) {
        const unsigned short* __restrict__ A = (p == 0) ? A0 : (p == 1) ? A1 : A2;
        const unsigned short* __restrict__ W = (p == 0) ? W0 : (p == 1) ? W1 : W2;
        bf16x8 af[4];
        const unsigned short* ap = A + (size_t)r * D + g * 8;
        #pragma unroll
        for (int ks = 0; ks < 4; ++ks)
            af[ks] = *reinterpret_cast<const bf16x8*>(ap + ks * 32);
        #pragma unroll
        for (int ct = 0; ct < 8; ++ct) {
            const unsigned short* wp = W + (size_t)(ct * 16 + m) * D + g * 8;
            #pragma unroll
            for (int ks = 0; ks < 4; ++ks) {
                bf16x8 bfv = *reinterpret_cast<const bf16x8*>(wp + ks * 32);
                acc[ct] = __builtin_amdgcn_mfma_f32_16x16x32_bf16(af[ks], bfv, acc[ct], 0, 0, 0);
            }
        }
    }

    // epilogue: C/D layout col=lane&15, row=(lane>>4)*4+reg
    const int r0 = rbase + g * 4;
    #pragma unroll
    for (int ct = 0; ct < 8; ++ct) {
        int col = ct * 16 + m;
        #pragma unroll
        for (int j = 0; j < 4; ++j) {
            int rr = r0 + j;
            if (rr < N) out[(size_t)rr * D + col] = acc[ct][j];
        }
    }
}

// ---------------------------------------------------------------------------
extern "C" void kernel_launch(void* const* d_in, const int* in_sizes, int n_in,
                              void* d_out, int out_size, void* d_ws, size_t ws_size,
                              hipStream_t stream)
{
    const float* x_A        = (const float*)d_in[0];
    const float* x_B        = (const float*)d_in[1];
    const float* W_msg_ab1  = (const float*)d_in[2];
    const float* W_self_ab1 = (const float*)d_in[3];
    const float* W_msg_ab2  = (const float*)d_in[4];
    const float* W_self_ab2 = (const float*)d_in[5];
    const float* W_msg_ba   = (const float*)d_in[6];
    const float* W_self_ba  = (const float*)d_in[7];
    const int* src_ab1 = (const int*)d_in[8];
    const int* dst_ab1 = (const int*)d_in[9];
    const int* src_ab2 = (const int*)d_in[10];
    const int* dst_ab2 = (const int*)d_in[11];
    const int* src_ba  = (const int*)d_in[12];
    const int* dst_ba  = (const int*)d_in[13];

    float* out_A = (float*)d_out;
    float* out_B = out_A + (size_t)NA * D;

    // workspace layout (~132.6 MB)
    char* ws = (char*)d_ws;
    unsigned short* xb  = (unsigned short*)ws;            // 51.2 MB (xbA | xbB)
    unsigned short* xbA = xb;
    unsigned short* xbB = xb + (size_t)NA * D;
    unsigned short* G0  = xbB + (size_t)NB * D;           // 25.6 MB
    unsigned short* G1  = G0 + (size_t)NA * D;            // 25.6 MB
    int* cur   = (int*)(G1 + (size_t)NA * D);             // 1.2 MB (3 x NA)
    int* slots = cur + 3 * NA;                            // 28.8 MB (3 x NA x CAP)
    unsigned short* WT = (unsigned short*)(slots + (size_t)3 * NA * CAP);  // 160 KB
    unsigned short* WT_mba  = WT;
    unsigned short* WT_sba  = WT + 1 * D * D;
    unsigned short* WT_mab1 = WT + 2 * D * D;
    unsigned short* WT_mab2 = WT + 3 * D * D;
    unsigned short* WT_sab  = WT + 4 * D * D;

    const dim3 blk(256);
    const int cv_blocks   = (2 * NA * D / 8) / 256;        // 12500
    const int fa_blocks   = (3 * NE + 255) / 256;          // 4688
    const int gs_blocks   = (NA * 16) / 256;               // 6250
    const int gm_blocks   = (NA + 63) / 64;                // 1563

    prep_weights_kernel<<<5 * D * D / 256, blk, 0, stream>>>(
        WT, W_msg_ba, W_self_ba, W_msg_ab1, W_msg_ab2, W_self_ab1, W_self_ab2);
    convert_x_kernel<<<cv_blocks, blk, 0, stream>>>(xb, x_A, x_B);
    hipMemsetAsync(cur, 0, 3 * (size_t)NA * sizeof(int), stream);
    fill_all_kernel<<<fa_blocks, blk, 0, stream>>>(
        cur, slots, src_ba, dst_ba, src_ab1, dst_ab1, src_ab2, dst_ab2);

    // out_A = segsum(x_B[src_ba]) @ Wm_ba + x_A @ Ws_ba
    gather_sum_kernel<<<gs_blocks, blk, 0, stream>>>(G0, xbB, cur, slots, NA);
    mfma_gemm_kernel<2><<<gm_blocks, blk, 0, stream>>>(
        out_A, G0, xbA, nullptr, WT_mba, WT_sba, nullptr, NA);

    // out_B = segsum(x_A[src_ab1]) @ Wm_ab1 + segsum(x_A[src_ab2]) @ Wm_ab2
    //       + x_B @ (Ws_ab1 + Ws_ab2)
    gather_sum_kernel<<<gs_blocks, blk, 0, stream>>>(
        G0, xbA, cur + NA, slots + (size_t)NA * CAP, NB);
    gather_sum_kernel<<<gs_blocks, blk, 0, stream>>>(
        G1, xbA, cur + 2 * NA, slots + (size_t)2 * NA * CAP, NB);
    mfma_gemm_kernel<3><<<gm_blocks, blk, 0, stream>>>(
        out_B, G0, G1, xbB, WT_mab1, WT_mab2, WT_sab, NB);
}